// Round 1
// baseline (1165.181 us; speedup 1.0000x reference)
//
#include <hip/hip_runtime.h>
#include <hip/hip_bf16.h>
#include <math.h>

#define Tn 1024
#define Bn 16
#define Hn 1024
#define Sn 2048
#define LDP 40  // padded LDS row stride in bf16 elems (tile K=32, pad to 40 to spread banks)

typedef __attribute__((ext_vector_type(8))) short bf16x8;
typedef __attribute__((ext_vector_type(4))) float f32x4;

__device__ __forceinline__ unsigned short f2bf(float x) {
  unsigned u = __float_as_uint(x);
  u += 0x7fffu + ((u >> 16) & 1u);  // round-to-nearest-even to bf16
  return (unsigned short)(u >> 16);
}
__device__ __forceinline__ float bf2f(unsigned short h) {
  return __uint_as_float(((unsigned)h) << 16);
}
__device__ __forceinline__ void split2(float x, unsigned short& hi, unsigned short& lo) {
  hi = f2bf(x);
  lo = f2bf(x - bf2f(hi));
}

// Stage 128(rows) x 32(k) f32 tile (k contiguous, row stride ldr floats) into hi/lo LDS [128][LDP].
__device__ __forceinline__ void stage_rows(const float* __restrict__ g, size_t ldr,
                                           unsigned short* __restrict__ Lhi,
                                           unsigned short* __restrict__ Llo, int tid) {
#pragma unroll
  for (int it = 0; it < 4; ++it) {
    const int r = (tid >> 3) + it * 32;
    const int c = (tid & 7) * 4;
    const float4 v = *(const float4*)(g + (size_t)r * ldr + c);
    unsigned short h0, h1, h2, h3, l0, l1, l2, l3;
    split2(v.x, h0, l0); split2(v.y, h1, l1); split2(v.z, h2, l2); split2(v.w, h3, l3);
    uint2 hp, lp;
    hp.x = (unsigned)h0 | ((unsigned)h1 << 16);
    hp.y = (unsigned)h2 | ((unsigned)h3 << 16);
    lp.x = (unsigned)l0 | ((unsigned)l1 << 16);
    lp.y = (unsigned)l2 | ((unsigned)l3 << 16);
    *(uint2*)&Lhi[r * LDP + c] = hp;
    *(uint2*)&Llo[r * LDP + c] = lp;
  }
}

// Stage 32(k rows) x 128(n cols) f32 tile TRANSPOSED into LDS [n][k] ([128][LDP]).
// Bank-staggered scalar writes (j permuted per lane) to avoid full same-bank serialization.
__device__ __forceinline__ void stage_trans(const float* __restrict__ g, size_t ldr,
                                            unsigned short* __restrict__ Lhi,
                                            unsigned short* __restrict__ Llo, int tid) {
  const int t5 = tid & 31;
#pragma unroll
  for (int it = 0; it < 4; ++it) {
    const int kk = (tid >> 5) + it * 8;
    const int n0 = t5 * 4;
    const float4 v = *(const float4*)(g + (size_t)kk * ldr + n0);
#pragma unroll
    for (int jj = 0; jj < 4; ++jj) {
      const int j = (jj + t5 + (t5 >> 2)) & 3;  // spread across 8 bank groups
      const float val = (j == 0) ? v.x : (j == 1) ? v.y : (j == 2) ? v.z : v.w;
      unsigned short h, l;
      split2(val, h, l);
      Lhi[(n0 + j) * LDP + kk] = h;
      Llo[(n0 + j) * LDP + kk] = l;
    }
  }
}

// One K=32 step: 4x4 fragments per wave, bf16x3 split-precision MFMA.
__device__ __forceinline__ void mfma_tile(const unsigned short* __restrict__ Ah,
                                          const unsigned short* __restrict__ Al,
                                          const unsigned short* __restrict__ Bh,
                                          const unsigned short* __restrict__ Bl,
                                          int wm, int wn, int lane, f32x4 (&acc)[4][4]) {
  const int r16 = lane & 15;
  const int kh = (lane >> 4) * 8;
  bf16x8 ah[4], al[4], bh[4], bl[4];
#pragma unroll
  for (int i = 0; i < 4; ++i) {
    const int off = (wm + i * 16 + r16) * LDP + kh;
    ah[i] = *(const bf16x8*)&Ah[off];
    al[i] = *(const bf16x8*)&Al[off];
  }
#pragma unroll
  for (int j = 0; j < 4; ++j) {
    const int off = (wn + j * 16 + r16) * LDP + kh;
    bh[j] = *(const bf16x8*)&Bh[off];
    bl[j] = *(const bf16x8*)&Bl[off];
  }
#pragma unroll
  for (int i = 0; i < 4; ++i)
#pragma unroll
    for (int j = 0; j < 4; ++j) {
      acc[i][j] = __builtin_amdgcn_mfma_f32_16x16x32_bf16(ah[i], bh[j], acc[i][j], 0, 0, 0);
      acc[i][j] = __builtin_amdgcn_mfma_f32_16x16x32_bf16(ah[i], bl[j], acc[i][j], 0, 0, 0);
      acc[i][j] = __builtin_amdgcn_mfma_f32_16x16x32_bf16(al[i], bh[j], acc[i][j], 0, 0, 0);
    }
}

// scores[b][t][s] = sum_h output[t][b][h] * memory[s][b][h]
__global__ __launch_bounds__(256, 2) void k_scores(const float* __restrict__ outp,
                                                   const float* __restrict__ mem,
                                                   float* __restrict__ attn) {
  __shared__ unsigned short Ah[128 * LDP], Al[128 * LDP], Bh[128 * LDP], Bl[128 * LDP];
  const int tid = threadIdx.x;
  const int lane = tid & 63;
  const int wv = tid >> 6;
  const int wm = (wv >> 1) * 64, wn = (wv & 1) * 64;
  const int bs = blockIdx.x * 128;
  const int bt = blockIdx.y * 128;
  const int b = blockIdx.z;
  const f32x4 fz = {0.f, 0.f, 0.f, 0.f};
  f32x4 acc[4][4];
#pragma unroll
  for (int i = 0; i < 4; ++i)
#pragma unroll
    for (int j = 0; j < 4; ++j) acc[i][j] = fz;

  const float* Ag = outp + ((size_t)bt * Bn + b) * Hn;  // rows: t, stride B*H
  const float* Bg = mem + ((size_t)bs * Bn + b) * Hn;   // rows: s, stride B*H
  for (int k0 = 0; k0 < Hn; k0 += 32) {
    stage_rows(Ag + k0, (size_t)Bn * Hn, Ah, Al, tid);
    stage_rows(Bg + k0, (size_t)Bn * Hn, Bh, Bl, tid);
    __syncthreads();
    mfma_tile(Ah, Al, Bh, Bl, wm, wn, lane, acc);
    __syncthreads();
  }
  const int r16 = lane & 15;
  const int rq = (lane >> 4) * 4;
  float* obase = attn + (size_t)b * Tn * Sn;
#pragma unroll
  for (int i = 0; i < 4; ++i)
#pragma unroll
    for (int q = 0; q < 4; ++q) {
      const int t = bt + wm + i * 16 + rq + q;
#pragma unroll
      for (int j = 0; j < 4; ++j) {
        const int s = bs + wn + j * 16 + r16;
        obase[(size_t)t * Sn + s] = acc[i][j][q];
      }
    }
}

// Row softmax over S with mask, in place on the attn region.
__global__ __launch_bounds__(256) void k_softmax(float* __restrict__ attn,
                                                 const unsigned char* __restrict__ mask) {
  const int row = blockIdx.x;  // b*T + t
  float* p = attn + (size_t)row * Sn;
  const unsigned char* mrow = mask + (size_t)row * Sn;
  const int tid = threadIdx.x;
  const int lane = tid & 63;
  const int wv = tid >> 6;
  const float4 a = *(const float4*)(p + tid * 8);
  const float4 c = *(const float4*)(p + tid * 8 + 4);
  const unsigned long long mv = *(const unsigned long long*)(mrow + tid * 8);
  float x[8] = {a.x, a.y, a.z, a.w, c.x, c.y, c.z, c.w};
#pragma unroll
  for (int j = 0; j < 8; ++j)
    if ((mv >> (8 * j)) & 0xffull) x[j] = -INFINITY;
  float mx = x[0];
#pragma unroll
  for (int j = 1; j < 8; ++j) mx = fmaxf(mx, x[j]);
#pragma unroll
  for (int off = 32; off; off >>= 1) mx = fmaxf(mx, __shfl_xor(mx, off, 64));
  __shared__ float redmax[4], redsum[4];
  if (lane == 0) redmax[wv] = mx;
  __syncthreads();
  mx = fmaxf(fmaxf(redmax[0], redmax[1]), fmaxf(redmax[2], redmax[3]));
  float e[8];
  float s = 0.f;
#pragma unroll
  for (int j = 0; j < 8; ++j) {
    e[j] = __expf(x[j] - mx);
    s += e[j];
  }
#pragma unroll
  for (int off = 32; off; off >>= 1) s += __shfl_xor(s, off, 64);
  if (lane == 0) redsum[wv] = s;
  __syncthreads();
  s = redsum[0] + redsum[1] + redsum[2] + redsum[3];
  const float inv = 1.0f / s;
  float4 o0 = {e[0] * inv, e[1] * inv, e[2] * inv, e[3] * inv};
  float4 o1 = {e[4] * inv, e[5] * inv, e[6] * inv, e[7] * inv};
  *(float4*)(p + tid * 8) = o0;
  *(float4*)(p + tid * 8 + 4) = o1;
}

// ctx[t][b][h] = sum_s attn[b][t][s] * memory[s][b][h]   (B staged transposed)
__global__ __launch_bounds__(256, 2) void k_context(const float* __restrict__ attn,
                                                    const float* __restrict__ mem,
                                                    float* __restrict__ ctx) {
  __shared__ unsigned short Ah[128 * LDP], Al[128 * LDP], Bh[128 * LDP], Bl[128 * LDP];
  const int tid = threadIdx.x;
  const int lane = tid & 63;
  const int wv = tid >> 6;
  const int wm = (wv >> 1) * 64, wn = (wv & 1) * 64;
  const int bh_ = blockIdx.x * 128;  // h tile
  const int bt = blockIdx.y * 128;   // t tile
  const int b = blockIdx.z;
  const f32x4 fz = {0.f, 0.f, 0.f, 0.f};
  f32x4 acc[4][4];
#pragma unroll
  for (int i = 0; i < 4; ++i)
#pragma unroll
    for (int j = 0; j < 4; ++j) acc[i][j] = fz;

  const float* Ag = attn + ((size_t)b * Tn + bt) * Sn;  // rows: t, stride S
  const float* Bg = mem + (size_t)b * Hn + bh_;         // element (s,h): Bg + s*B*H + (h-bh_)
  for (int k0 = 0; k0 < Sn; k0 += 32) {
    stage_rows(Ag + k0, (size_t)Sn, Ah, Al, tid);
    stage_trans(Bg + (size_t)k0 * Bn * Hn, (size_t)Bn * Hn, Bh, Bl, tid);
    __syncthreads();
    mfma_tile(Ah, Al, Bh, Bl, wm, wn, lane, acc);
    __syncthreads();
  }
  const int r16 = lane & 15;
  const int rq = (lane >> 4) * 4;
#pragma unroll
  for (int i = 0; i < 4; ++i)
#pragma unroll
    for (int q = 0; q < 4; ++q) {
      const int t = bt + wm + i * 16 + rq + q;
#pragma unroll
      for (int j = 0; j < 4; ++j) {
        const int h = bh_ + wn + j * 16 + r16;
        ctx[((size_t)t * Bn + b) * Hn + h] = acc[i][j][q];
      }
    }
}

// out[r][h] = tanh( sum_k ctx[r][k]*W[h][k] + sum_k outp[r][k]*W[h][H+k] + bias[h] ), r = t*B+b
__global__ __launch_bounds__(256, 2) void k_final(const float* __restrict__ ctx,
                                                  const float* __restrict__ outp,
                                                  const float* __restrict__ W,
                                                  const float* __restrict__ bias,
                                                  float* __restrict__ out) {
  __shared__ unsigned short Ah[128 * LDP], Al[128 * LDP], Bh[128 * LDP], Bl[128 * LDP];
  const int tid = threadIdx.x;
  const int lane = tid & 63;
  const int wv = tid >> 6;
  const int wm = (wv >> 1) * 64, wn = (wv & 1) * 64;
  const int bh_ = blockIdx.x * 128;  // output h tile (N)
  const int bm = blockIdx.y * 128;   // row tile over M = T*B
  const f32x4 fz = {0.f, 0.f, 0.f, 0.f};
  f32x4 acc[4][4];
#pragma unroll
  for (int i = 0; i < 4; ++i)
#pragma unroll
    for (int j = 0; j < 4; ++j) acc[i][j] = fz;

  for (int k0 = 0; k0 < 2 * Hn; k0 += 32) {
    const float* Ag = (k0 < Hn) ? (ctx + (size_t)bm * Hn + k0)
                                : (outp + (size_t)bm * Hn + (k0 - Hn));
    stage_rows(Ag, (size_t)Hn, Ah, Al, tid);
    stage_rows(W + (size_t)bh_ * (2 * Hn) + k0, (size_t)(2 * Hn), Bh, Bl, tid);
    __syncthreads();
    mfma_tile(Ah, Al, Bh, Bl, wm, wn, lane, acc);
    __syncthreads();
  }
  const int r16 = lane & 15;
  const int rq = (lane >> 4) * 4;
#pragma unroll
  for (int i = 0; i < 4; ++i)
#pragma unroll
    for (int q = 0; q < 4; ++q) {
      const int r = bm + wm + i * 16 + rq + q;
#pragma unroll
      for (int j = 0; j < 4; ++j) {
        const int h = bh_ + wn + j * 16 + r16;
        out[(size_t)r * Hn + h] = tanhf(acc[i][j][q] + bias[h]);
      }
    }
}

extern "C" void kernel_launch(void* const* d_in, const int* in_sizes, int n_in,
                              void* d_out, int out_size, void* d_ws, size_t ws_size,
                              hipStream_t stream) {
  const float* outp = (const float*)d_in[0];
  const float* mem = (const float*)d_in[1];
  const unsigned char* mask = (const unsigned char*)d_in[2];
  const float* W = (const float*)d_in[3];
  const float* bias = (const float*)d_in[4];
  float* out = (float*)d_out;                       // (T,B,H) f32
  float* attn = out + (size_t)Tn * Bn * Hn;         // (B,T,S) f32 (output 2)
  float* ctx = (float*)d_ws;                        // (T,B,H) f32 scratch, 67 MB

  k_scores<<<dim3(Sn / 128, Tn / 128, Bn), 256, 0, stream>>>(outp, mem, attn);
  k_softmax<<<dim3(Bn * Tn), 256, 0, stream>>>(attn, mask);
  k_context<<<dim3(Hn / 128, Tn / 128, Bn), 256, 0, stream>>>(attn, mem, ctx);
  k_final<<<dim3(Hn / 128, (Tn * Bn) / 128), 256, 0, stream>>>(ctx, outp, W, bias, out);
}

// Round 2
// 629.311 us; speedup vs baseline: 1.8515x; 1.8515x over previous
//
#include <hip/hip_runtime.h>
#include <hip/hip_bf16.h>
#include <math.h>

#define Tn 1024
#define Bn 16
#define Hn 1024
#define Sn 2048
#define LDP 40  // padded LDS row stride (bf16 elems) for the split-precision scores kernel

typedef __attribute__((ext_vector_type(8))) short bf16x8;
typedef __attribute__((ext_vector_type(8))) unsigned short u16x8;
typedef __attribute__((ext_vector_type(4))) float f32x4;

__device__ __forceinline__ unsigned short f2bf(float x) {
  unsigned u = __float_as_uint(x);
  u += 0x7fffu + ((u >> 16) & 1u);  // round-to-nearest-even to bf16
  return (unsigned short)(u >> 16);
}
__device__ __forceinline__ float bf2f(unsigned short h) {
  return __uint_as_float(((unsigned)h) << 16);
}
__device__ __forceinline__ void split2(float x, unsigned short& hi, unsigned short& lo) {
  hi = f2bf(x);
  lo = f2bf(x - bf2f(hi));
}

// async global->LDS, 16B per lane; LDS dest = wave-uniform base + lane*16
__device__ __forceinline__ void gload16(const void* g, void* l) {
  __builtin_amdgcn_global_load_lds((const __attribute__((address_space(1))) void*)g,
                                   (__attribute__((address_space(3))) void*)l, 16, 0, 0);
}

// ---------- conversion kernels ----------

// stream f32 -> bf16, 8 elems/thread
__global__ __launch_bounds__(256) void k_cvt8(const float* __restrict__ src,
                                              unsigned short* __restrict__ dst, int n8) {
  const int i = blockIdx.x * 256 + threadIdx.x;
  if (i >= n8) return;
  const float4 a = *(const float4*)(src + (size_t)i * 8);
  const float4 c = *(const float4*)(src + (size_t)i * 8 + 4);
  u16x8 u;
  u[0] = f2bf(a.x); u[1] = f2bf(a.y); u[2] = f2bf(a.z); u[3] = f2bf(a.w);
  u[4] = f2bf(c.x); u[5] = f2bf(c.y); u[6] = f2bf(c.z); u[7] = f2bf(c.w);
  *(u16x8*)(dst + (size_t)i * 8) = u;
}

// mem (S,B,H) f32 -> memT (B,H,S) bf16, 64x64 LDS tile transpose per block
__global__ __launch_bounds__(256) void k_tr_mem(const float* __restrict__ mem,
                                                unsigned short* __restrict__ memT) {
  __shared__ unsigned short L[64 * 72];
  const int t = threadIdx.x;
  const int h0 = blockIdx.x * 64, s0 = blockIdx.y * 64, b = blockIdx.z;
#pragma unroll
  for (int p = 0; p < 4; ++p) {
    const int fid = p * 256 + t;
    const int s_l = fid >> 4;        // 0..63
    const int h_l = (fid & 15) * 4;  // 0..60
    const float4 v = *(const float4*)(mem + ((size_t)(s0 + s_l) * Bn + b) * Hn + h0 + h_l);
    unsigned short e[4] = {f2bf(v.x), f2bf(v.y), f2bf(v.z), f2bf(v.w)};
#pragma unroll
    for (int i0 = 0; i0 < 4; ++i0) {
      const int i = (i0 + (t & 3)) & 3;  // bank stagger
      L[(h_l + i) * 72 + s_l] = e[i];
    }
  }
  __syncthreads();
#pragma unroll
  for (int p = 0; p < 2; ++p) {
    const int cid = p * 256 + t;
    const int h_l = cid >> 3;  // 0..63
    const int c = cid & 7;     // 16B chunk along s
    const bf16x8 vv = *(const bf16x8*)&L[h_l * 72 + c * 8];
    *(bf16x8*)(memT + ((size_t)b * Hn + h0 + h_l) * Sn + s0 + c * 8) = vv;
  }
}

// ---------- split-precision scores GEMM (unchanged from round 1) ----------

__device__ __forceinline__ void stage_rows(const float* __restrict__ g, size_t ldr,
                                           unsigned short* __restrict__ Lhi,
                                           unsigned short* __restrict__ Llo, int tid) {
#pragma unroll
  for (int it = 0; it < 4; ++it) {
    const int r = (tid >> 3) + it * 32;
    const int c = (tid & 7) * 4;
    const float4 v = *(const float4*)(g + (size_t)r * ldr + c);
    unsigned short h0, h1, h2, h3, l0, l1, l2, l3;
    split2(v.x, h0, l0); split2(v.y, h1, l1); split2(v.z, h2, l2); split2(v.w, h3, l3);
    uint2 hp, lp;
    hp.x = (unsigned)h0 | ((unsigned)h1 << 16);
    hp.y = (unsigned)h2 | ((unsigned)h3 << 16);
    lp.x = (unsigned)l0 | ((unsigned)l1 << 16);
    lp.y = (unsigned)l2 | ((unsigned)l3 << 16);
    *(uint2*)&Lhi[r * LDP + c] = hp;
    *(uint2*)&Llo[r * LDP + c] = lp;
  }
}

__device__ __forceinline__ void mfma_tile(const unsigned short* __restrict__ Ah,
                                          const unsigned short* __restrict__ Al,
                                          const unsigned short* __restrict__ Bh,
                                          const unsigned short* __restrict__ Bl,
                                          int wm, int wn, int lane, f32x4 (&acc)[4][4]) {
  const int r16 = lane & 15;
  const int kh = (lane >> 4) * 8;
  bf16x8 ah[4], al[4], bh[4], bl[4];
#pragma unroll
  for (int i = 0; i < 4; ++i) {
    const int off = (wm + i * 16 + r16) * LDP + kh;
    ah[i] = *(const bf16x8*)&Ah[off];
    al[i] = *(const bf16x8*)&Al[off];
  }
#pragma unroll
  for (int j = 0; j < 4; ++j) {
    const int off = (wn + j * 16 + r16) * LDP + kh;
    bh[j] = *(const bf16x8*)&Bh[off];
    bl[j] = *(const bf16x8*)&Bl[off];
  }
#pragma unroll
  for (int i = 0; i < 4; ++i)
#pragma unroll
    for (int j = 0; j < 4; ++j) {
      acc[i][j] = __builtin_amdgcn_mfma_f32_16x16x32_bf16(ah[i], bh[j], acc[i][j], 0, 0, 0);
      acc[i][j] = __builtin_amdgcn_mfma_f32_16x16x32_bf16(ah[i], bl[j], acc[i][j], 0, 0, 0);
      acc[i][j] = __builtin_amdgcn_mfma_f32_16x16x32_bf16(al[i], bh[j], acc[i][j], 0, 0, 0);
    }
}

// scores[b][t][s] = sum_h output[t][b][h] * memory[s][b][h]  (bf16x3 split precision)
__global__ __launch_bounds__(256, 2) void k_scores(const float* __restrict__ outp,
                                                   const float* __restrict__ mem,
                                                   float* __restrict__ attn) {
  __shared__ unsigned short Ah[128 * LDP], Al[128 * LDP], Bh[128 * LDP], Bl[128 * LDP];
  const int tid = threadIdx.x;
  const int lane = tid & 63;
  const int wv = tid >> 6;
  const int wm = (wv >> 1) * 64, wn = (wv & 1) * 64;
  const int bs = blockIdx.x * 128;
  const int bt = blockIdx.y * 128;
  const int b = blockIdx.z;
  const f32x4 fz = {0.f, 0.f, 0.f, 0.f};
  f32x4 acc[4][4];
#pragma unroll
  for (int i = 0; i < 4; ++i)
#pragma unroll
    for (int j = 0; j < 4; ++j) acc[i][j] = fz;

  const float* Ag = outp + ((size_t)bt * Bn + b) * Hn;
  const float* Bg = mem + ((size_t)bs * Bn + b) * Hn;
  for (int k0 = 0; k0 < Hn; k0 += 32) {
    stage_rows(Ag + k0, (size_t)Bn * Hn, Ah, Al, tid);
    stage_rows(Bg + k0, (size_t)Bn * Hn, Bh, Bl, tid);
    __syncthreads();
    mfma_tile(Ah, Al, Bh, Bl, wm, wn, lane, acc);
    __syncthreads();
  }
  const int r16 = lane & 15;
  const int rq = (lane >> 4) * 4;
  float* obase = attn + (size_t)b * Tn * Sn;
#pragma unroll
  for (int i = 0; i < 4; ++i)
#pragma unroll
    for (int q = 0; q < 4; ++q) {
      const int t = bt + wm + i * 16 + rq + q;
#pragma unroll
      for (int j = 0; j < 4; ++j) {
        const int s = bs + wn + j * 16 + r16;
        obase[(size_t)t * Sn + s] = acc[i][j][q];
      }
    }
}

// ---------- softmax (also emits bf16 probabilities) ----------

__global__ __launch_bounds__(256) void k_softmax(float* __restrict__ attn,
                                                 const unsigned char* __restrict__ mask,
                                                 unsigned short* __restrict__ attnbf) {
  const int row = blockIdx.x;  // b*T + t
  float* p = attn + (size_t)row * Sn;
  const unsigned char* mrow = mask + (size_t)row * Sn;
  const int tid = threadIdx.x;
  const int lane = tid & 63;
  const int wv = tid >> 6;
  const float4 a = *(const float4*)(p + tid * 8);
  const float4 c = *(const float4*)(p + tid * 8 + 4);
  const unsigned long long mv = *(const unsigned long long*)(mrow + tid * 8);
  float x[8] = {a.x, a.y, a.z, a.w, c.x, c.y, c.z, c.w};
#pragma unroll
  for (int j = 0; j < 8; ++j)
    if ((mv >> (8 * j)) & 0xffull) x[j] = -INFINITY;
  float mx = x[0];
#pragma unroll
  for (int j = 1; j < 8; ++j) mx = fmaxf(mx, x[j]);
#pragma unroll
  for (int off = 32; off; off >>= 1) mx = fmaxf(mx, __shfl_xor(mx, off, 64));
  __shared__ float redmax[4], redsum[4];
  if (lane == 0) redmax[wv] = mx;
  __syncthreads();
  mx = fmaxf(fmaxf(redmax[0], redmax[1]), fmaxf(redmax[2], redmax[3]));
  float e[8];
  float s = 0.f;
#pragma unroll
  for (int j = 0; j < 8; ++j) {
    e[j] = __expf(x[j] - mx);
    s += e[j];
  }
#pragma unroll
  for (int off = 32; off; off >>= 1) s += __shfl_xor(s, off, 64);
  if (lane == 0) redsum[wv] = s;
  __syncthreads();
  s = redsum[0] + redsum[1] + redsum[2] + redsum[3];
  const float inv = 1.0f / s;
  float o[8];
#pragma unroll
  for (int j = 0; j < 8; ++j) o[j] = e[j] * inv;
  float4 o0 = {o[0], o[1], o[2], o[3]};
  float4 o1 = {o[4], o[5], o[6], o[7]};
  *(float4*)(p + tid * 8) = o0;
  *(float4*)(p + tid * 8 + 4) = o1;
  u16x8 ub;
#pragma unroll
  for (int j = 0; j < 8; ++j) ub[j] = f2bf(o[j]);
  *(u16x8*)(attnbf + (size_t)row * Sn + tid * 8) = ub;
}

// ---------- single-bf16 GEMM building blocks (linear LDS + global_load_lds) ----------

// stage a 128-row x 64-col bf16 tile (row stride ldr elems) into linear LDS [128][64]
__device__ __forceinline__ void stage128x64(const unsigned short* __restrict__ g, size_t ldr,
                                            unsigned short* __restrict__ lds, int tid) {
  const int wv = tid >> 6;
  const int row = tid >> 3;            // 0..31
  const size_t coff = (size_t)(tid & 7) * 8;  // bf16 elems
#pragma unroll
  for (int q = 0; q < 4; ++q) {
    gload16(g + (size_t)(q * 32 + row) * ldr + coff, lds + q * 2048 + wv * 512);
  }
}

__device__ __forceinline__ void mfma64(const unsigned short* __restrict__ A,
                                       const unsigned short* __restrict__ B,
                                       int wm, int wn, int lane, f32x4 (&acc)[4][4]) {
  const int r16 = lane & 15;
  const int kh = (lane >> 4) * 8;
#pragma unroll
  for (int ks = 0; ks < 2; ++ks) {
    bf16x8 a[4], bb[4];
#pragma unroll
    for (int i = 0; i < 4; ++i) a[i] = *(const bf16x8*)&A[(wm + i * 16 + r16) * 64 + ks * 32 + kh];
#pragma unroll
    for (int j = 0; j < 4; ++j) bb[j] = *(const bf16x8*)&B[(wn + j * 16 + r16) * 64 + ks * 32 + kh];
#pragma unroll
    for (int i = 0; i < 4; ++i)
#pragma unroll
      for (int j = 0; j < 4; ++j)
        acc[i][j] = __builtin_amdgcn_mfma_f32_16x16x32_bf16(a[i], bb[j], acc[i][j], 0, 0, 0);
  }
}

// ctx[t][b][h] = sum_s attnbf[b][t][s] * memT[b][h][s]  (single bf16)
__global__ __launch_bounds__(256, 3) void k_context(const unsigned short* __restrict__ attnbf,
                                                    const unsigned short* __restrict__ memT,
                                                    unsigned short* __restrict__ ctxbf) {
  __shared__ unsigned short As[128 * 64], Bs[128 * 64];
  const int tid = threadIdx.x, lane = tid & 63, wv = tid >> 6;
  const int wm = (wv >> 1) * 64, wn = (wv & 1) * 64;
  const int bh = blockIdx.x * 128, bt = blockIdx.y * 128, b = blockIdx.z;
  const f32x4 fz = {0.f, 0.f, 0.f, 0.f};
  f32x4 acc[4][4];
#pragma unroll
  for (int i = 0; i < 4; ++i)
#pragma unroll
    for (int j = 0; j < 4; ++j) acc[i][j] = fz;

  const unsigned short* Ag = attnbf + ((size_t)b * Tn + bt) * Sn;
  const unsigned short* Bg = memT + ((size_t)b * Hn + bh) * Sn;
  for (int k0 = 0; k0 < Sn; k0 += 64) {
    stage128x64(Ag + k0, Sn, As, tid);
    stage128x64(Bg + k0, Sn, Bs, tid);
    __syncthreads();
    mfma64(As, Bs, wm, wn, lane, acc);
    __syncthreads();
  }
  const int r16 = lane & 15, rq = (lane >> 4) * 4;
#pragma unroll
  for (int i = 0; i < 4; ++i)
#pragma unroll
    for (int q = 0; q < 4; ++q) {
      const int t = bt + wm + i * 16 + rq + q;
#pragma unroll
      for (int j = 0; j < 4; ++j) {
        const int h = bh + wn + j * 16 + r16;
        ctxbf[((size_t)t * Bn + b) * Hn + h] = f2bf(acc[i][j][q]);
      }
    }
}

// out[r][h] = tanh( sum_k [ctx|outp][r][k] * W[h][k] + bias[h] ),  r = t*B + b
__global__ __launch_bounds__(256, 3) void k_final(const unsigned short* __restrict__ ctxbf,
                                                  const unsigned short* __restrict__ outpbf,
                                                  const unsigned short* __restrict__ Wbf,
                                                  const float* __restrict__ bias,
                                                  float* __restrict__ out) {
  __shared__ unsigned short As[128 * 64], Bs[128 * 64];
  const int tid = threadIdx.x, lane = tid & 63, wv = tid >> 6;
  const int wm = (wv >> 1) * 64, wn = (wv & 1) * 64;
  const int bh = blockIdx.x * 128, bm = blockIdx.y * 128;
  const f32x4 fz = {0.f, 0.f, 0.f, 0.f};
  f32x4 acc[4][4];
#pragma unroll
  for (int i = 0; i < 4; ++i)
#pragma unroll
    for (int j = 0; j < 4; ++j) acc[i][j] = fz;

  for (int k0 = 0; k0 < 2 * Hn; k0 += 64) {
    const unsigned short* Ag = (k0 < Hn) ? (ctxbf + (size_t)bm * Hn + k0)
                                         : (outpbf + (size_t)bm * Hn + (k0 - Hn));
    stage128x64(Ag, Hn, As, tid);
    stage128x64(Wbf + (size_t)bh * (2 * Hn) + k0, 2 * Hn, Bs, tid);
    __syncthreads();
    mfma64(As, Bs, wm, wn, lane, acc);
    __syncthreads();
  }
  const int r16 = lane & 15, rq = (lane >> 4) * 4;
  float bj[4];
#pragma unroll
  for (int j = 0; j < 4; ++j) bj[j] = bias[bh + wn + j * 16 + r16];
#pragma unroll
  for (int i = 0; i < 4; ++i)
#pragma unroll
    for (int q = 0; q < 4; ++q) {
      const int r = bm + wm + i * 16 + rq + q;
#pragma unroll
      for (int j = 0; j < 4; ++j) {
        const int h = bh + wn + j * 16 + r16;
        out[(size_t)r * Hn + h] = tanhf(acc[i][j][q] + bj[j]);
      }
    }
}

extern "C" void kernel_launch(void* const* d_in, const int* in_sizes, int n_in,
                              void* d_out, int out_size, void* d_ws, size_t ws_size,
                              hipStream_t stream) {
  const float* outp = (const float*)d_in[0];
  const float* mem = (const float*)d_in[1];
  const unsigned char* mask = (const unsigned char*)d_in[2];
  const float* W = (const float*)d_in[3];
  const float* bias = (const float*)d_in[4];
  float* out = (float*)d_out;                // (T,B,H) f32
  float* attn = out + (size_t)Tn * Bn * Hn;  // (B,T,S) f32 (output 2)

  // workspace layout (bf16 planes), total ~196 MB
  char* w = (char*)d_ws;
  unsigned short* memT = (unsigned short*)w;                       // [B][H][S]  64 MB
  unsigned short* attnbf = (unsigned short*)(w + (size_t)67108864);   // [B][T][S]  64 MB
  unsigned short* ctxbf = (unsigned short*)(w + (size_t)134217728);   // [T][B][H]  32 MB
  unsigned short* outpbf = (unsigned short*)(w + (size_t)167772160);  // [T][B][H]  32 MB
  unsigned short* Wbf = (unsigned short*)(w + (size_t)201326592);     // [H][2H]     4 MB

  k_cvt8<<<dim3((Tn * Bn * Hn / 8) / 256), 256, 0, stream>>>(outp, outpbf, Tn * Bn * Hn / 8);
  k_cvt8<<<dim3((Hn * 2 * Hn / 8) / 256), 256, 0, stream>>>(W, Wbf, Hn * 2 * Hn / 8);
  k_tr_mem<<<dim3(Hn / 64, Sn / 64, Bn), 256, 0, stream>>>(mem, memT);

  k_scores<<<dim3(Sn / 128, Tn / 128, Bn), 256, 0, stream>>>(outp, mem, attn);
  k_softmax<<<dim3(Bn * Tn), 256, 0, stream>>>(attn, mask, attnbf);
  k_context<<<dim3(Hn / 128, Tn / 128, Bn), 256, 0, stream>>>(attnbf, memT, ctxbf);
  k_final<<<dim3(Hn / 128, (Tn * Bn) / 128), 256, 0, stream>>>(ctxbf, outpbf, Wbf, bias, out);
}

// Round 3
// 565.888 us; speedup vs baseline: 2.0590x; 1.1121x over previous
//
#include <hip/hip_runtime.h>
#include <hip/hip_bf16.h>
#include <math.h>

#define Tn 1024
#define Bn 16
#define Hn 1024
#define Sn 2048

typedef __attribute__((ext_vector_type(8))) short bf16x8;
typedef __attribute__((ext_vector_type(8))) unsigned short u16x8;
typedef __attribute__((ext_vector_type(4))) float f32x4;

__device__ __forceinline__ unsigned short f2bf(float x) {
  unsigned u = __float_as_uint(x);
  u += 0x7fffu + ((u >> 16) & 1u);  // round-to-nearest-even to bf16
  return (unsigned short)(u >> 16);
}
__device__ __forceinline__ float bf2f(unsigned short h) {
  return __uint_as_float(((unsigned)h) << 16);
}

// async global->LDS, 16B per lane; LDS dest = wave-uniform base + lane*16
__device__ __forceinline__ void gload16(const void* g, void* l) {
  __builtin_amdgcn_global_load_lds((const __attribute__((address_space(1))) void*)g,
                                   (__attribute__((address_space(3))) void*)l, 16, 0, 0);
}

// ---------- conversion kernels ----------

// (rows,B,H) f32 -> b-major hi/lo bf16 planes [B][rows][H]
__global__ __launch_bounds__(256) void k_split_plane(const float* __restrict__ src,
                                                     unsigned short* __restrict__ hiP,
                                                     unsigned short* __restrict__ loP,
                                                     int rows) {
  const int i = blockIdx.x * 256 + threadIdx.x;  // 8-elem group id
  const int h8 = i & (Hn / 8 - 1);
  const int rem = i >> 7;
  const int b = rem & (Bn - 1);
  const int r = rem >> 4;
  const float4 a = *(const float4*)(src + (size_t)i * 8);
  const float4 c = *(const float4*)(src + (size_t)i * 8 + 4);
  const float v[8] = {a.x, a.y, a.z, a.w, c.x, c.y, c.z, c.w};
  u16x8 hv, lv;
#pragma unroll
  for (int j = 0; j < 8; ++j) {
    const unsigned short h = f2bf(v[j]);
    hv[j] = h;
    lv[j] = f2bf(v[j] - bf2f(h));
  }
  const size_t dst = ((size_t)b * rows + r) * Hn + h8 * 8;
  *(u16x8*)(hiP + dst) = hv;
  *(u16x8*)(loP + dst) = lv;
}

// stream f32 -> bf16 (hi only), 8 elems/thread (for W)
__global__ __launch_bounds__(256) void k_cvt8(const float* __restrict__ src,
                                              unsigned short* __restrict__ dst, int n8) {
  const int i = blockIdx.x * 256 + threadIdx.x;
  if (i >= n8) return;
  const float4 a = *(const float4*)(src + (size_t)i * 8);
  const float4 c = *(const float4*)(src + (size_t)i * 8 + 4);
  u16x8 u;
  u[0] = f2bf(a.x); u[1] = f2bf(a.y); u[2] = f2bf(a.z); u[3] = f2bf(a.w);
  u[4] = f2bf(c.x); u[5] = f2bf(c.y); u[6] = f2bf(c.z); u[7] = f2bf(c.w);
  *(u16x8*)(dst + (size_t)i * 8) = u;
}

// memH [B][S][H] bf16 -> memT [B][H][S] bf16, 64x64 LDS tile transpose
__global__ __launch_bounds__(256) void k_trH(const unsigned short* __restrict__ memH,
                                             unsigned short* __restrict__ memT) {
  __shared__ unsigned short L[64 * 72];
  const int t = threadIdx.x;
  const int h0 = blockIdx.x * 64, s0 = blockIdx.y * 64, b = blockIdx.z;
#pragma unroll
  for (int p = 0; p < 2; ++p) {
    const int fid = p * 256 + t;  // 0..511
    const int s_l = fid >> 3;     // 0..63
    const int c = fid & 7;        // h chunk (8 elems)
    const u16x8 v = *(const u16x8*)(memH + ((size_t)b * Sn + s0 + s_l) * Hn + h0 + c * 8);
#pragma unroll
    for (int e = 0; e < 8; ++e) L[(c * 8 + e) * 72 + s_l] = v[e];
  }
  __syncthreads();
#pragma unroll
  for (int p = 0; p < 2; ++p) {
    const int cid = p * 256 + t;
    const int h_l = cid >> 3;
    const int c = cid & 7;  // 16B chunk along s
    const u16x8 vv = *(const u16x8*)&L[h_l * 72 + c * 8];
    *(u16x8*)(memT + ((size_t)b * Hn + h0 + h_l) * Sn + s0 + c * 8) = vv;
  }
}

// ---------- staging helpers ----------

// stage a 128-row x 32-col bf16 tile (row stride ldr elems) into linear LDS [128][32]
__device__ __forceinline__ void stage128x32(const unsigned short* __restrict__ g, size_t ldr,
                                            unsigned short* __restrict__ lds, int tid) {
  const int wv = tid >> 6;
  const int row = tid >> 2;                   // 0..63
  const size_t coff = (size_t)(tid & 3) * 8;  // bf16 elems (16B chunks)
#pragma unroll
  for (int q = 0; q < 2; ++q)
    gload16(g + (size_t)(q * 64 + row) * ldr + coff, lds + q * 2048 + wv * 512);
}

// stage a 128-row x 64-col bf16 tile into linear LDS [128][64]
__device__ __forceinline__ void stage128x64(const unsigned short* __restrict__ g, size_t ldr,
                                            unsigned short* __restrict__ lds, int tid) {
  const int wv = tid >> 6;
  const int row = tid >> 3;                   // 0..31
  const size_t coff = (size_t)(tid & 7) * 8;  // bf16 elems
#pragma unroll
  for (int q = 0; q < 4; ++q)
    gload16(g + (size_t)(q * 32 + row) * ldr + coff, lds + q * 2048 + wv * 512);
}

// ---------- scores GEMM: pre-split planes, bf16x3 split precision ----------
// scores[b][t][s] = sum_h outp[t][b][h] * mem[s][b][h]

__global__ __launch_bounds__(256, 3) void k_scores(const unsigned short* __restrict__ oH,
                                                   const unsigned short* __restrict__ oL,
                                                   const unsigned short* __restrict__ mH,
                                                   const unsigned short* __restrict__ mL,
                                                   float* __restrict__ attn) {
  __shared__ unsigned short AsH[128 * 32], AsL[128 * 32], BsH[128 * 32], BsL[128 * 32];
  const int tid = threadIdx.x, lane = tid & 63, wv = tid >> 6;
  const int wm = (wv >> 1) * 64, wn = (wv & 1) * 64;
  const int bs = blockIdx.x * 128, bt = blockIdx.y * 128, b = blockIdx.z;
  const f32x4 fz = {0.f, 0.f, 0.f, 0.f};
  f32x4 acc[4][4];
#pragma unroll
  for (int i = 0; i < 4; ++i)
#pragma unroll
    for (int j = 0; j < 4; ++j) acc[i][j] = fz;

  const unsigned short* AgH = oH + ((size_t)b * Tn + bt) * Hn;
  const unsigned short* AgL = oL + ((size_t)b * Tn + bt) * Hn;
  const unsigned short* BgH = mH + ((size_t)b * Sn + bs) * Hn;
  const unsigned short* BgL = mL + ((size_t)b * Sn + bs) * Hn;
  const int r16 = lane & 15, kh = (lane >> 4) * 8;
  for (int k0 = 0; k0 < Hn; k0 += 32) {
    stage128x32(AgH + k0, Hn, AsH, tid);
    stage128x32(AgL + k0, Hn, AsL, tid);
    stage128x32(BgH + k0, Hn, BsH, tid);
    stage128x32(BgL + k0, Hn, BsL, tid);
    __syncthreads();
    bf16x8 ah[4], al[4];
#pragma unroll
    for (int i = 0; i < 4; ++i) {
      ah[i] = *(const bf16x8*)&AsH[(wm + i * 16 + r16) * 32 + kh];
      al[i] = *(const bf16x8*)&AsL[(wm + i * 16 + r16) * 32 + kh];
    }
#pragma unroll
    for (int j = 0; j < 4; ++j) {
      const bf16x8 bh = *(const bf16x8*)&BsH[(wn + j * 16 + r16) * 32 + kh];
      const bf16x8 bl = *(const bf16x8*)&BsL[(wn + j * 16 + r16) * 32 + kh];
#pragma unroll
      for (int i = 0; i < 4; ++i) {
        acc[i][j] = __builtin_amdgcn_mfma_f32_16x16x32_bf16(ah[i], bh, acc[i][j], 0, 0, 0);
        acc[i][j] = __builtin_amdgcn_mfma_f32_16x16x32_bf16(ah[i], bl, acc[i][j], 0, 0, 0);
        acc[i][j] = __builtin_amdgcn_mfma_f32_16x16x32_bf16(al[i], bh, acc[i][j], 0, 0, 0);
      }
    }
    __syncthreads();
  }
  const int rq = (lane >> 4) * 4;
  float* obase = attn + (size_t)b * Tn * Sn;
#pragma unroll
  for (int i = 0; i < 4; ++i)
#pragma unroll
    for (int q = 0; q < 4; ++q) {
      const int t = bt + wm + i * 16 + rq + q;
#pragma unroll
      for (int j = 0; j < 4; ++j) {
        const int s = bs + wn + j * 16 + r16;
        obase[(size_t)t * Sn + s] = acc[i][j][q];
      }
    }
}

// ---------- softmax (also emits bf16 probabilities) ----------

__global__ __launch_bounds__(256) void k_softmax(float* __restrict__ attn,
                                                 const unsigned char* __restrict__ mask,
                                                 unsigned short* __restrict__ attnbf) {
  const int row = blockIdx.x;  // b*T + t
  float* p = attn + (size_t)row * Sn;
  const unsigned char* mrow = mask + (size_t)row * Sn;
  const int tid = threadIdx.x;
  const int lane = tid & 63;
  const int wv = tid >> 6;
  const float4 a = *(const float4*)(p + tid * 8);
  const float4 c = *(const float4*)(p + tid * 8 + 4);
  const unsigned long long mv = *(const unsigned long long*)(mrow + tid * 8);
  float x[8] = {a.x, a.y, a.z, a.w, c.x, c.y, c.z, c.w};
#pragma unroll
  for (int j = 0; j < 8; ++j)
    if ((mv >> (8 * j)) & 0xffull) x[j] = -INFINITY;
  float mx = x[0];
#pragma unroll
  for (int j = 1; j < 8; ++j) mx = fmaxf(mx, x[j]);
#pragma unroll
  for (int off = 32; off; off >>= 1) mx = fmaxf(mx, __shfl_xor(mx, off, 64));
  __shared__ float redmax[4], redsum[4];
  if (lane == 0) redmax[wv] = mx;
  __syncthreads();
  mx = fmaxf(fmaxf(redmax[0], redmax[1]), fmaxf(redmax[2], redmax[3]));
  float e[8];
  float s = 0.f;
#pragma unroll
  for (int j = 0; j < 8; ++j) {
    e[j] = __expf(x[j] - mx);
    s += e[j];
  }
#pragma unroll
  for (int off = 32; off; off >>= 1) s += __shfl_xor(s, off, 64);
  if (lane == 0) redsum[wv] = s;
  __syncthreads();
  s = redsum[0] + redsum[1] + redsum[2] + redsum[3];
  const float inv = 1.0f / s;
  float o[8];
#pragma unroll
  for (int j = 0; j < 8; ++j) o[j] = e[j] * inv;
  float4 o0 = {o[0], o[1], o[2], o[3]};
  float4 o1 = {o[4], o[5], o[6], o[7]};
  *(float4*)(p + tid * 8) = o0;
  *(float4*)(p + tid * 8 + 4) = o1;
  u16x8 ub;
#pragma unroll
  for (int j = 0; j < 8; ++j) ub[j] = f2bf(o[j]);
  *(u16x8*)(attnbf + (size_t)row * Sn + tid * 8) = ub;
}

// ---------- single-bf16 GEMMs ----------

__device__ __forceinline__ void mfma64(const unsigned short* __restrict__ A,
                                       const unsigned short* __restrict__ B,
                                       int wm, int wn, int lane, f32x4 (&acc)[4][4]) {
  const int r16 = lane & 15;
  const int kh = (lane >> 4) * 8;
#pragma unroll
  for (int ks = 0; ks < 2; ++ks) {
    bf16x8 a[4], bb[4];
#pragma unroll
    for (int i = 0; i < 4; ++i) a[i] = *(const bf16x8*)&A[(wm + i * 16 + r16) * 64 + ks * 32 + kh];
#pragma unroll
    for (int j = 0; j < 4; ++j) bb[j] = *(const bf16x8*)&B[(wn + j * 16 + r16) * 64 + ks * 32 + kh];
#pragma unroll
    for (int i = 0; i < 4; ++i)
#pragma unroll
      for (int j = 0; j < 4; ++j)
        acc[i][j] = __builtin_amdgcn_mfma_f32_16x16x32_bf16(a[i], bb[j], acc[i][j], 0, 0, 0);
  }
}

// ctx[b][t][h] = sum_s attnbf[b][t][s] * memT[b][h][s]  (single bf16)
__global__ __launch_bounds__(256, 3) void k_context(const unsigned short* __restrict__ attnbf,
                                                    const unsigned short* __restrict__ memT,
                                                    unsigned short* __restrict__ ctxB) {
  __shared__ unsigned short As[128 * 64], Bs[128 * 64];
  const int tid = threadIdx.x, lane = tid & 63, wv = tid >> 6;
  const int wm = (wv >> 1) * 64, wn = (wv & 1) * 64;
  const int bh = blockIdx.x * 128, bt = blockIdx.y * 128, b = blockIdx.z;
  const f32x4 fz = {0.f, 0.f, 0.f, 0.f};
  f32x4 acc[4][4];
#pragma unroll
  for (int i = 0; i < 4; ++i)
#pragma unroll
    for (int j = 0; j < 4; ++j) acc[i][j] = fz;

  const unsigned short* Ag = attnbf + ((size_t)b * Tn + bt) * Sn;
  const unsigned short* Bg = memT + ((size_t)b * Hn + bh) * Sn;
  for (int k0 = 0; k0 < Sn; k0 += 64) {
    stage128x64(Ag + k0, Sn, As, tid);
    stage128x64(Bg + k0, Sn, Bs, tid);
    __syncthreads();
    mfma64(As, Bs, wm, wn, lane, acc);
    __syncthreads();
  }
  const int r16 = lane & 15, rq = (lane >> 4) * 4;
#pragma unroll
  for (int i = 0; i < 4; ++i)
#pragma unroll
    for (int q = 0; q < 4; ++q) {
      const int t = bt + wm + i * 16 + rq + q;
#pragma unroll
      for (int j = 0; j < 4; ++j) {
        const int h = bh + wn + j * 16 + r16;
        ctxB[((size_t)b * Tn + t) * Hn + h] = f2bf(acc[i][j][q]);
      }
    }
}

// out[t][b][h] = tanh( sum_k [ctxB|outpH][b*T+t][k] * W[h][k] + bias[h] )
__global__ __launch_bounds__(256, 3) void k_final(const unsigned short* __restrict__ ctxB,
                                                  const unsigned short* __restrict__ outpH,
                                                  const unsigned short* __restrict__ Wbf,
                                                  const float* __restrict__ bias,
                                                  float* __restrict__ out) {
  __shared__ unsigned short As[128 * 64], Bs[128 * 64];
  const int tid = threadIdx.x, lane = tid & 63, wv = tid >> 6;
  const int wm = (wv >> 1) * 64, wn = (wv & 1) * 64;
  const int bh = blockIdx.x * 128, bm = blockIdx.y * 128;  // rows r' = b*T + t
  const f32x4 fz = {0.f, 0.f, 0.f, 0.f};
  f32x4 acc[4][4];
#pragma unroll
  for (int i = 0; i < 4; ++i)
#pragma unroll
    for (int j = 0; j < 4; ++j) acc[i][j] = fz;

  for (int k0 = 0; k0 < 2 * Hn; k0 += 64) {
    const unsigned short* Ag = (k0 < Hn) ? (ctxB + (size_t)bm * Hn + k0)
                                         : (outpH + (size_t)bm * Hn + (k0 - Hn));
    stage128x64(Ag, Hn, As, tid);
    stage128x64(Wbf + (size_t)bh * (2 * Hn) + k0, 2 * Hn, Bs, tid);
    __syncthreads();
    mfma64(As, Bs, wm, wn, lane, acc);
    __syncthreads();
  }
  const int r16 = lane & 15, rq = (lane >> 4) * 4;
  float bj[4];
#pragma unroll
  for (int j = 0; j < 4; ++j) bj[j] = bias[bh + wn + j * 16 + r16];
#pragma unroll
  for (int i = 0; i < 4; ++i)
#pragma unroll
    for (int q = 0; q < 4; ++q) {
      const int r = bm + wm + i * 16 + rq + q;  // b*T + t
      const int b = r >> 10, t = r & (Tn - 1);
#pragma unroll
      for (int j = 0; j < 4; ++j) {
        const int h = bh + wn + j * 16 + r16;
        out[((size_t)t * Bn + b) * Hn + h] = tanhf(acc[i][j][q] + bj[j]);
      }
    }
}

extern "C" void kernel_launch(void* const* d_in, const int* in_sizes, int n_in,
                              void* d_out, int out_size, void* d_ws, size_t ws_size,
                              hipStream_t stream) {
  const float* outp = (const float*)d_in[0];
  const float* mem = (const float*)d_in[1];
  const unsigned char* mask = (const unsigned char*)d_in[2];
  const float* W = (const float*)d_in[3];
  const float* bias = (const float*)d_in[4];
  float* out = (float*)d_out;                // (T,B,H) f32
  float* attn = out + (size_t)Tn * Bn * Hn;  // (B,T,S) f32 (output 2)

  // workspace: peak 196 MB with aliasing (all regions 16B-aligned)
  char* w = (char*)d_ws;
  unsigned short* memH  = (unsigned short*)(w);                        // [B][S][H] 64MB (live: split..scores,trH)
  unsigned short* memL  = (unsigned short*)(w + ((size_t)64 << 20));   // [B][S][H] 64MB (live: split..scores)
  unsigned short* outpH = (unsigned short*)(w + ((size_t)128 << 20));  // [B][T][H] 32MB (live: split..final)
  unsigned short* outpL = (unsigned short*)(w + ((size_t)160 << 20));  // [B][T][H] 32MB (live: split..scores)
  unsigned short* Wbf   = (unsigned short*)(w + ((size_t)192 << 20));  // [H][2H]    4MB
  // aliases (written only after scores has consumed the originals):
  unsigned short* memT   = memL;   // [B][H][S] 64MB (trH..context)
  unsigned short* attnbf = memH;   // [B][T][S] 64MB (softmax..context)
  unsigned short* ctxB   = outpL;  // [B][T][H] 32MB (context..final)

  k_split_plane<<<dim3((Tn * Bn * Hn / 8) / 256), 256, 0, stream>>>(outp, outpH, outpL, Tn);
  k_split_plane<<<dim3((Sn * Bn * Hn / 8) / 256), 256, 0, stream>>>(mem, memH, memL, Sn);
  k_cvt8<<<dim3((Hn * 2 * Hn / 8) / 256), 256, 0, stream>>>(W, Wbf, Hn * 2 * Hn / 8);

  k_scores<<<dim3(Sn / 128, Tn / 128, Bn), 256, 0, stream>>>(outpH, outpL, memH, memL, attn);
  k_trH<<<dim3(Hn / 64, Sn / 64, Bn), 256, 0, stream>>>(memH, memT);
  k_softmax<<<dim3(Bn * Tn), 256, 0, stream>>>(attn, mask, attnbf);
  k_context<<<dim3(Hn / 128, Tn / 128, Bn), 256, 0, stream>>>(attnbf, memT, ctxB);
  k_final<<<dim3(Hn / 128, (Tn * Bn) / 128), 256, 0, stream>>>(ctxB, outpH, Wbf, bias, out);
}